// Round 13
// baseline (195.440 us; speedup 1.0000x reference)
//
#include <hip/hip_runtime.h>

#define H 1024
#define W 1024
#define K 11
#define RAD 5
#define ROWS 64              /* 74/64 = 1.16 redundancy (R0-proven best) */
#define NIN (ROWS + K - 1)   /* 74 input rows per strip */
#define BW 256               /* output cols per block; 64 per wave */
#define SWW 80               /* per-wave staged floats per image (74 used, padded) */

typedef float v2f __attribute__((ext_vector_type(2)));

__global__ void zero_out_kernel(float* out) {
    if (threadIdx.x == 0) out[0] = 0.0f;
}

__device__ __forceinline__ v2f pkfma(v2f a, v2f b, v2f c) {
    return __builtin_elementwise_fma(a, b, c);
}

/* Vertical tap: slot S at phase P holds the row at distance d=(P-S+11)%11 from
   the newest; weight gw[10-d]. P,S literals -> constant indices. */
#define SSIM_TAP(P,S) do {                                                    \
    const float w = gw[10 - ((P - S + 11) % 11)];                             \
    const v2f w2v = { w, w };                                                 \
    mu = pkfma(w2v, q##S, mu);                                                \
    sq = pkfma(w2v, t##S, sq);                                                \
    xy = fmaf(w, u##S, xy);                                                   \
} while (0)

/* One row-phase, WAVE-PRIVATE LDS staging, NO BARRIER:
   each wave owns 64 output cols and its own LDS region; LDS write->read is
   same-wave (DS ops complete in order / lgkmcnt-guarded by the compiler), so
   the 74 per-phase __syncthreads of R9-R12 are deleted. Waves drift freely and
   stagger to cover each other's stalls — the barrier-lockstep theory for the
   46% residual stall at 54% VALUBusy (R12: global-load latency acquitted,
   2-deep pipeline was neutral). 2-deep hold regs kept (R12 incumbent). */
#define SSIM_PHASE_WV(P) do {                                                 \
    const int i = base + (P);                                                 \
    if (i < NIN) {                                                            \
        /* ---- 1. issue global loads of row i+2 into 'n' regs ---- */        \
        float n1m, n2m, n1t = 0.f, n2t = 0.f;                                 \
        {                                                                     \
            int rn = rin0 + i + 2;                                            \
            rn = min(max(rn, 0), H - 1);                                      \
            const float* __restrict__ r1 = p1 + (size_t)rn * W;               \
            const float* __restrict__ r2 = p2 + (size_t)rn * W;               \
            n1m = r1[gmc] * okm;                                              \
            n2m = r2[gmc] * okm;                                              \
            if (lane < 10) { n1t = r1[gtc] * okt; n2t = r2[gtc] * okt; }      \
        }                                                                     \
        /* ---- 2. window of row i from this wave's LDS buffer ---- */        \
        const float* __restrict__ sA = wbase + (i & 1) * (2 * SWW);           \
        const float* __restrict__ sB = sA + SWW;                              \
        float x[11], y[11];                                                   \
        _Pragma("unroll")                                                     \
        for (int j = 0; j < 11; ++j) { x[j] = sA[lane + j]; y[j] = sB[lane + j]; } \
        /* ---- 3a. horizontal 11-tap, tap-paired packed fp32 ---- */         \
        v2f amx = {0.f,0.f}, amy = {0.f,0.f};                                 \
        v2f axx = {0.f,0.f}, ayy = {0.f,0.f}, axy = {0.f,0.f};                \
        _Pragma("unroll")                                                     \
        for (int e = 0; e < 5; ++e) {                                         \
            v2f w2 = { gw[2*e], gw[2*e+1] };                                  \
            v2f xp = { x[2*e], x[2*e+1] };                                    \
            v2f yp = { y[2*e], y[2*e+1] };                                    \
            v2f wxp = w2 * xp;                                                \
            v2f wyp = w2 * yp;                                                \
            amx += wxp; amy += wyp;                                           \
            axx = pkfma(wxp, xp, axx);                                        \
            ayy = pkfma(wyp, yp, ayy);                                        \
            axy = pkfma(wxp, yp, axy);                                        \
        }                                                                     \
        const float twx = gw[10] * x[10];                                     \
        const float twy = gw[10] * y[10];                                     \
        const float hmx = (amx.x + amx.y) + twx;                              \
        const float hmy = (amy.x + amy.y) + twy;                              \
        const float hxx = fmaf(twx, x[10], axx.x + axx.y);                    \
        const float hyy = fmaf(twy, y[10], ayy.x + ayy.y);                    \
        const float hxy = fmaf(twx, y[10], axy.x + axy.y);                    \
        {                                                                     \
            const int r = rin0 + i;                                           \
            const float sm = ((unsigned)r < (unsigned)H) ? 1.0f : 0.0f;       \
            const v2f sv = { sm, sm };                                        \
            q##P = sv * (v2f){ hmx, hmy };                                    \
            t##P = sv * (v2f){ hxx, hyy };                                    \
            u##P = sm * hxy;                                                  \
        }                                                                     \
        /* ---- 3b. vertical 11-tap + SSIM ---- */                            \
        if (i >= K - 1) {                                                     \
            v2f mu = {0.f,0.f}, sq = {0.f,0.f}; float xy = 0.f;               \
            SSIM_TAP(P,0); SSIM_TAP(P,1); SSIM_TAP(P,2); SSIM_TAP(P,3);       \
            SSIM_TAP(P,4); SSIM_TAP(P,5); SSIM_TAP(P,6); SSIM_TAP(P,7);       \
            SSIM_TAP(P,8); SSIM_TAP(P,9); SSIM_TAP(P,10);                     \
            const v2f m2 = mu * mu;                                           \
            const float mxy  = mu.x * mu.y;                                   \
            const v2f sg = sq - m2;                                           \
            const float sxyv = xy - mxy;                                      \
            const float num = fmaf(2.0f, mxy,  C1) * fmaf(2.0f, sxyv, C2);    \
            const float den = (m2.x + m2.y + C1) * (sg.x + sg.y + C2);        \
            acc += num * __builtin_amdgcn_rcpf(den);                          \
        }                                                                     \
        /* ---- 4. stage row i+1 (held regs) into the other buffer ---- */    \
        float* __restrict__ dA = wbase + ((i + 1) & 1) * (2 * SWW);           \
        float* __restrict__ dB = dA + SWW;                                    \
        dA[lane] = h1m;                                                       \
        dB[lane] = h2m;                                                       \
        if (lane < 10) { dA[64 + lane] = h1t; dB[64 + lane] = h2t; }          \
        h1m = n1m; h2m = n2m; h1t = n1t; h2t = n2t;                           \
    }                                                                         \
} while (0)

__launch_bounds__(256, 3)
__global__ void ssim_kernel(const float* __restrict__ img1,
                            const float* __restrict__ img2,
                            const float* __restrict__ kern,
                            float* __restrict__ out,
                            float inv_n) {
    __shared__ float swb[4][2][2][SWW];  /* [wave][parity][img][col] = 5120 B */
    __shared__ float wsum[4];

    const int tid  = threadIdx.x;
    const int lane = tid & 63;
    const int wid  = tid >> 6;
    float* wbase = &swb[wid][0][0][0];

    const int cb  = blockIdx.x * BW;
    const int wc0 = cb + wid * 64;       /* this wave's first output col */
    const int ry0 = blockIdx.y * ROWS;
    const int b   = blockIdx.z;

    // 1D gaussian = row sums of normalized 2D kernel (exact). Pin to SGPRs.
    float gw[K];
    #pragma unroll
    for (int t = 0; t < K; ++t) {
        float s = 0.0f;
        #pragma unroll
        for (int j = 0; j < K; ++j) s += kern[t * K + j];
        gw[t] = __int_as_float(__builtin_amdgcn_readfirstlane(__float_as_int(s)));
    }

    const float* __restrict__ p1 = img1 + (size_t)b * H * W;
    const float* __restrict__ p2 = img2 + (size_t)b * H * W;
    const int rin0 = ry0 - RAD;

    // Per-wave staging: main covers LDS[0..63] <- col wc0-5+lane; tail
    // (lane<10) covers LDS[64..73] <- col wc0+59+lane. Window of lane l =
    // offsets l..l+10 (cols wc0+l-5 .. wc0+l+5). Edges masked at stage.
    const int   gmc_raw = wc0 - 5 + lane;
    const float okm = ((unsigned)gmc_raw < (unsigned)W) ? 1.0f : 0.0f;
    const int   gmc = min(max(gmc_raw, 0), W - 1);
    const int   gtc_raw = wc0 + 59 + lane;
    const float okt = ((unsigned)gtc_raw < (unsigned)W) ? 1.0f : 0.0f;
    const int   gtc = min(gtc_raw, W - 1);

    // Ring in 33 NAMED registers (R2 lesson: no arrays across the backedge).
    const v2f z2 = {0.f, 0.f};
    v2f q0=z2,q1=z2,q2=z2,q3=z2,q4=z2,q5=z2,q6=z2,q7=z2,q8=z2,q9=z2,q10=z2;
    v2f t0=z2,t1=z2,t2=z2,t3=z2,t4=z2,t5=z2,t6=z2,t7=z2,t8=z2,t9=z2,t10=z2;
    float u0=0,u1=0,u2=0,u3=0,u4=0,u5=0,u6=0,u7=0,u8=0,u9=0,u10=0;
    float acc = 0.0f;
    const float C1 = 1e-4f;
    const float C2 = 9e-4f;

    // 2-deep pipeline hold regs (row i+1's values during phase i).
    float h1m, h2m, h1t = 0.f, h2t = 0.f;

    {   // prologue: stage strip row 0 into parity 0; row 1 into hold regs.
        // Same-wave LDS -> no barrier needed anywhere in the loop.
        const int r0 = min(max(rin0, 0), H - 1);
        const float* __restrict__ r1 = p1 + (size_t)r0 * W;
        const float* __restrict__ r2 = p2 + (size_t)r0 * W;
        wbase[lane]        = r1[gmc] * okm;
        wbase[SWW + lane]  = r2[gmc] * okm;
        if (lane < 10) {
            wbase[64 + lane]       = r1[gtc] * okt;
            wbase[SWW + 64 + lane] = r2[gtc] * okt;
        }
        const int rn = min(max(rin0 + 1, 0), H - 1);
        const float* __restrict__ s1 = p1 + (size_t)rn * W;
        const float* __restrict__ s2 = p2 + (size_t)rn * W;
        h1m = s1[gmc] * okm;
        h2m = s2[gmc] * okm;
        if (lane < 10) { h1t = s1[gtc] * okt; h2t = s2[gtc] * okt; }
    }

    // ROLLED outer loop (R6 win: ~11KB hot body, I$-resident), barrier-free.
    #pragma unroll 1
    for (int it = 0; it < 7; ++it) {
        const int base = it * K;
        SSIM_PHASE_WV(0);  SSIM_PHASE_WV(1);  SSIM_PHASE_WV(2);
        SSIM_PHASE_WV(3);  SSIM_PHASE_WV(4);  SSIM_PHASE_WV(5);
        SSIM_PHASE_WV(6);  SSIM_PHASE_WV(7);  SSIM_PHASE_WV(8);
        SSIM_PHASE_WV(9);  SSIM_PHASE_WV(10);
    }

    // Wave butterfly reduce -> cross-wave via LDS (single barrier) -> atomic.
    for (int off = 32; off > 0; off >>= 1)
        acc += __shfl_down(acc, off, 64);
    if (lane == 0) wsum[wid] = acc;
    __syncthreads();
    if (tid == 0) {
        const float s = wsum[0] + wsum[1] + wsum[2] + wsum[3];
        atomicAdd(out, s * inv_n);
    }
}

extern "C" void kernel_launch(void* const* d_in, const int* in_sizes, int n_in,
                              void* d_out, int out_size, void* d_ws, size_t ws_size,
                              hipStream_t stream) {
    const float* img1 = (const float*)d_in[0];
    const float* img2 = (const float*)d_in[1];
    const float* kern = (const float*)d_in[2];
    float* out = (float*)d_out;

    const int B = in_sizes[0] / (H * W);
    const float inv_n = 1.0f / ((float)B * (float)H * (float)W);

    zero_out_kernel<<<dim3(1), dim3(64), 0, stream>>>(out);

    dim3 grid(W / BW, H / ROWS, B);
    ssim_kernel<<<grid, dim3(256), 0, stream>>>(img1, img2, kern, out, inv_n);
}